// Round 1
// baseline (180.591 us; speedup 1.0000x reference)
//
#include <hip/hip_runtime.h>
#include <math.h>

// Problem constants (fixed by setup_inputs)
#define BB   8      // batch
#define NDET 200    // detections
#define KK   32     // prototypes
#define HP   138
#define WP   138
#define NP   (HP*WP)     // 19044 pixels at proto res
#define H0   550
#define W0   550
#define NPIX (H0*W0)     // 302500 output pixels
#define CC   3
#define POSEPS 1e-6f

// ---------------------------------------------------------------------------
// Kernel A: per-detection gaussian params + conf  -> params[b*N+n][8]
//   [0]=cx [1]=cy [2]=1/(2*sx^2) [3]=1/(2*sy^2) [4]=conf
// ---------------------------------------------------------------------------
__global__ void params_kernel(const float* __restrict__ loc,
                              const float* __restrict__ conf,
                              float* __restrict__ params) {
    int i = blockIdx.x * blockDim.x + threadIdx.x;
    if (i >= BB * NDET) return;
    float cx = loc[i * 4 + 0];
    float cy = loc[i * 4 + 1];
    float w  = fmaxf(loc[i * 4 + 2], 1e-3f);
    float h  = fmaxf(loc[i * 4 + 3], 1e-3f);
    params[i * 8 + 0] = cx;
    params[i * 8 + 1] = cy;
    params[i * 8 + 2] = 1.0f / (2.0f * w * w);
    params[i * 8 + 3] = 1.0f / (2.0f * h * h);
    params[i * 8 + 4] = conf[i];
    params[i * 8 + 5] = 0.0f;
    params[i * 8 + 6] = 0.0f;
    params[i * 8 + 7] = 0.0f;
}

// ---------------------------------------------------------------------------
// Kernel B (hot): final_conf[b, y*WP+x]
//   per pixel: loop n=0..199: d = proto[b,y,x,:]·mask[b,n,:]
//              mc = sigmoid(d)*exp(-gauss)*conf;  s1+=mc; s2+=mc*mc
//   final_conf = 1 - s2/(s1+eps)
// mask/params loads are wave-uniform -> expect s_load + v_fma(v,v,s).
// ---------------------------------------------------------------------------
__global__ __launch_bounds__(256) void conf_kernel(
    const float* __restrict__ proto,   // [B, HP, WP, KK]
    const float* __restrict__ mask,    // [B, NDET, KK]
    const float* __restrict__ params,  // [B*NDET, 8]
    float* __restrict__ fconf)         // [B, NP]
{
    const int b = blockIdx.y;
    const int p = blockIdx.x * blockDim.x + threadIdx.x;
    if (p >= NP) return;
    const int y = p / WP;
    const int x = p - y * WP;
    const float xs = (x + 0.5f) * (1.0f / WP);
    const float ys = (y + 0.5f) * (1.0f / HP);

    // proto vector for this pixel -> 32 VGPRs
    float pr[KK];
    const float* pp = proto + ((size_t)b * NP + p) * KK;
#pragma unroll
    for (int k = 0; k < KK; k++) pr[k] = pp[k];

    const float* mb = mask + b * NDET * KK;     // wave-uniform base
    const float* pm = params + b * NDET * 8;    // wave-uniform base

    float s1 = 0.0f, s2 = 0.0f;
#pragma unroll 2
    for (int n = 0; n < NDET; n++) {
        float d0 = 0.f, d1 = 0.f, d2 = 0.f, d3 = 0.f;
#pragma unroll
        for (int k = 0; k < KK; k += 4) {
            d0 = fmaf(pr[k + 0], mb[n * KK + k + 0], d0);
            d1 = fmaf(pr[k + 1], mb[n * KK + k + 1], d1);
            d2 = fmaf(pr[k + 2], mb[n * KK + k + 2], d2);
            d3 = fmaf(pr[k + 3], mb[n * KK + k + 3], d3);
        }
        const float d = (d0 + d1) + (d2 + d3);
        const float cx = pm[n * 8 + 0];
        const float cy = pm[n * 8 + 1];
        const float ia = pm[n * 8 + 2];
        const float ib = pm[n * 8 + 3];
        const float cf = pm[n * 8 + 4];
        const float dx = xs - cx;
        const float dy = ys - cy;
        const float e  = dx * dx * ia + dy * dy * ib;
        // attention = exp(-e) / (1 + exp(-d))
        const float att = __fdividef(__expf(-e), 1.0f + __expf(-d));
        const float mc  = att * cf;
        s1 += mc;
        s2 = fmaf(mc, mc, s2);
    }
    float f = 1.0f - s2 / (s1 + POSEPS);
    if (isnan(f)) f = 0.0f;
    fconf[b * NP + p] = f;
}

// ---------------------------------------------------------------------------
// Kernel C: fused bilinear-resize + weighted mean/var + global reduction.
// One thread per output pixel (i,j) of the 550x550 grid.
// jax.image.resize(linear, upsample): half-pixel centers, edge
// renormalization == index clamping.
// ---------------------------------------------------------------------------
__global__ __launch_bounds__(256) void var_kernel(
    const float* __restrict__ original, // [B, C, H0, W0]
    const float* __restrict__ fconf,    // [B, NP]
    float* __restrict__ out)            // scalar accumulator
{
    const int p = blockIdx.x * blockDim.x + threadIdx.x;
    float v = 0.0f;
    if (p < NPIX) {
        const int i = p / W0;
        const int j = p - i * W0;
        const float scale = (float)HP / (float)H0;  // 138/550
        const float syf = (i + 0.5f) * scale - 0.5f;
        const float sxf = (j + 0.5f) * scale - 0.5f;
        const float fy0 = floorf(syf);
        const float fx0 = floorf(sxf);
        const float wy = syf - fy0;
        const float wx = sxf - fx0;
        int y0 = (int)fy0, x0 = (int)fx0;
        int y1 = min(y0 + 1, HP - 1);
        int x1 = min(x0 + 1, WP - 1);
        y0 = max(y0, 0);
        x0 = max(x0, 0);

        float r[BB];
        float t = 0.0f;
#pragma unroll
        for (int b = 0; b < BB; b++) {
            const float* F = fconf + b * NP;
            const float v00 = F[y0 * WP + x0];
            const float v01 = F[y0 * WP + x1];
            const float v10 = F[y1 * WP + x0];
            const float v11 = F[y1 * WP + x1];
            const float top = (1.0f - wx) * v00 + wx * v01;
            const float bot = (1.0f - wx) * v10 + wx * v11;
            const float rb  = (1.0f - wy) * top + wy * bot;
            r[b] = rb;
            t += rb;
        }
        const float inv_t  = __fdividef(1.0f, t);            // mean uses t (no eps)
        const float inv_te = __fdividef(1.0f, t + POSEPS);   // var uses t+eps
#pragma unroll
        for (int c = 0; c < CC; c++) {
            float s = 0.0f;
            float o[BB];
#pragma unroll
            for (int b = 0; b < BB; b++) {
                o[b] = original[(size_t)(b * CC + c) * NPIX + p];
                s = fmaf(o[b], r[b], s);
            }
            const float m = s * inv_t;
#pragma unroll
            for (int b = 0; b < BB; b++) {
                const float dd = o[b] - m;
                v += dd * dd * r[b];
            }
        }
        v *= inv_te;
    }
    // block reduction: wave shuffle then LDS across 4 waves
    for (int off = 32; off > 0; off >>= 1) v += __shfl_down(v, off, 64);
    __shared__ float red[4];
    const int lane = threadIdx.x & 63;
    const int wid  = threadIdx.x >> 6;
    if (lane == 0) red[wid] = v;
    __syncthreads();
    if (threadIdx.x == 0) {
        const float s = red[0] + red[1] + red[2] + red[3];
        // result = sum(weighted_var) / K * B = sum * 8/32 = sum * 0.25
        atomicAdd(out, s * 0.25f);
    }
}

// ---------------------------------------------------------------------------
extern "C" void kernel_launch(void* const* d_in, const int* in_sizes, int n_in,
                              void* d_out, int out_size, void* d_ws, size_t ws_size,
                              hipStream_t stream) {
    const float* original = (const float*)d_in[0]; // [8,3,550,550]
    const float* loc      = (const float*)d_in[1]; // [8,200,4]
    const float* mask     = (const float*)d_in[2]; // [8,200,32]
    const float* conf     = (const float*)d_in[3]; // [8,200]
    const float* proto    = (const float*)d_in[4]; // [8,138,138,32]
    float* out = (float*)d_out;

    // workspace layout
    float* params = (float*)d_ws;                        // 1600*8*4 = 51200 B
    float* fconf  = (float*)((char*)d_ws + 51200);       // 8*19044*4 = 609408 B

    hipMemsetAsync(out, 0, sizeof(float), stream);

    params_kernel<<<(BB * NDET + 255) / 256, 256, 0, stream>>>(loc, conf, params);

    dim3 gridB((NP + 255) / 256, BB);
    conf_kernel<<<gridB, 256, 0, stream>>>(proto, mask, params, fconf);

    var_kernel<<<(NPIX + 255) / 256, 256, 0, stream>>>(original, fconf, out);
}

// Round 2
// 127.687 us; speedup vs baseline: 1.4143x; 1.4143x over previous
//
#include <hip/hip_runtime.h>
#include <math.h>

// Problem constants
#define BB   8
#define NDET 200
#define NDP  208      // dets padded to 13*16
#define NCH  13       // det chunks of 16
#define KK   32
#define HP   138
#define WP   138
#define WPAD 144      // x padded to 9*16
#define NXT  9        // x tiles of 16
#define NP   (HP*WP)
#define H0   550
#define W0   550
#define NPIX (H0*W0)
#define CC   3
#define POSEPS 1e-6f

typedef __attribute__((ext_vector_type(8))) short  short8;
typedef __attribute__((ext_vector_type(4))) float  floatx4;

// Workspace layout (bytes):
//  afrag: BB*NCH*64 lanes * 16 B  = 106,496   @ 0        (bf16 A-fragments of mask)
//  gx:    BB*NDP*WPAD * 4         = 958,464   @ 106,496  (exp(-dx^2*ia), 0-padded)
//  gyc:   BB*HP*NDP * 4           = 918,528   @ 1,064,960 (conf*exp(-dy^2*ib))
//  fconf: NP*BB * 4               = 609,408   @ 1,983,488 (final_conf, pixel-major/batch-inner)
#define OFF_AFRAG 0
#define OFF_GX    106496
#define OFF_GYC   1064960
#define OFF_FCONF 1983488

__device__ inline unsigned short f32_to_bf16(float f) {
    union { float f; unsigned u; } v; v.f = f;
    unsigned r = v.u + 0x7FFFu + ((v.u >> 16) & 1u);   // RNE
    return (unsigned short)(r >> 16);
}

// ---------------------------------------------------------------------------
// prep: gaussian tables + bf16 mask A-fragments (all independent, one grid)
// ---------------------------------------------------------------------------
__global__ __launch_bounds__(256) void prep_kernel(
    const float* __restrict__ loc,   // [B,NDET,4]
    const float* __restrict__ conf,  // [B,NDET]
    const float* __restrict__ mask,  // [B,NDET,KK]
    char* __restrict__ ws)
{
    const int idx = blockIdx.x * 256 + threadIdx.x;
    float* gx  = (float*)(ws + OFF_GX);
    float* gyc = (float*)(ws + OFF_GYC);
    const int W1 = BB * NDP * WPAD;     // 239,616
    const int W2 = BB * HP * NDP;       // 229,632
    const int W3 = BB * NCH * 64;       //   6,656
    if (idx < W1) {
        int b = idx / (NDP * WPAD); int r = idx - b * (NDP * WPAD);
        int n = r / WPAD;           int x = r - n * WPAD;
        float v = 0.0f;
        if (n < NDET && x < WP) {
            const float* l = loc + (b * NDET + n) * 4;
            float cx = l[0];
            float w  = fmaxf(l[2], 1e-3f);
            float ia = 1.0f / (2.0f * w * w);
            float dx = (x + 0.5f) * (1.0f / WP) - cx;
            v = __expf(-dx * dx * ia);
        }
        gx[idx] = v;
    } else if (idx < W1 + W2) {
        int k = idx - W1;
        int b = k / (HP * NDP); int r = k - b * (HP * NDP);
        int y = r / NDP;        int n = r - y * NDP;
        float v = 0.0f;
        if (n < NDET) {
            const float* l = loc + (b * NDET + n) * 4;
            float cy = l[1];
            float h  = fmaxf(l[3], 1e-3f);
            float ib = 1.0f / (2.0f * h * h);
            float dy = (y + 0.5f) * (1.0f / HP) - cy;
            v = conf[b * NDET + n] * __expf(-dy * dy * ib);
        }
        gyc[k] = v;
    } else if (idx < W1 + W2 + W3) {
        int k = idx - W1 - W2;         // (b*NCH + c)*64 + L
        int L = k & 63; int bc = k >> 6;
        int c = bc % NCH; int b = bc / NCH;
        int det = c * 16 + (L & 15);
        int k0  = (L >> 4) * 8;
        unsigned o[4] = {0u, 0u, 0u, 0u};
        if (det < NDET) {
            const float* m = mask + (b * NDET + det) * KK + k0;
#pragma unroll
            for (int j = 0; j < 4; j++) {
                unsigned lo = f32_to_bf16(m[2 * j]);
                unsigned hi = f32_to_bf16(m[2 * j + 1]);
                o[j] = lo | (hi << 16);
            }
        }
        unsigned* dst = (unsigned*)(ws + OFF_AFRAG) + k * 4;
        dst[0] = o[0]; dst[1] = o[1]; dst[2] = o[2]; dst[3] = o[3];
    }
}

// ---------------------------------------------------------------------------
// conf (hot): one wave = 16 pixels (same row y) x all 208 dets.
// D = mask_tile(16x32) x proto_slice^T(32x16) via mfma_f32_16x16x32_bf16.
// D mapping: col(pixel)=lane&15, row(det-in-chunk)=(lane>>4)*4+reg.
// A layout: A[m=lane&15][k=(lane>>4)*8+j]  (precomputed afrag)
// B layout: B[n=lane&15][k=(lane>>4)*8+j]  (proto is [pixel][k] row-major)
// ---------------------------------------------------------------------------
__global__ __launch_bounds__(256) void conf_kernel(
    const float* __restrict__ proto,  // [B,HP,WP,KK]
    const char* __restrict__ ws,
    float* __restrict__ fconf)        // [NP][BB]
{
    const int wave = blockIdx.x * 4 + (threadIdx.x >> 6);
    const int L    = threadIdx.x & 63;
    const int b    = wave / (HP * NXT);
    int rem        = wave - b * (HP * NXT);
    const int y    = rem / NXT;
    const int xt   = rem - y * NXT;
    const int x0   = xt * 16;
    const int q    = L >> 4;
    const int c15  = L & 15;
    const int xl   = min(x0 + c15, WP - 1);   // clamped for proto load only

    const short8* af  = (const short8*)(ws + OFF_AFRAG) + (size_t)b * NCH * 64;
    const float*  gx  = (const float*)(ws + OFF_GX) + (size_t)b * NDP * WPAD;
    const float*  gyc = (const float*)(ws + OFF_GYC) + ((size_t)b * HP + y) * NDP;

    // B fragment: proto[b][y][xl][q*8 .. q*8+7] -> 8 bf16
    const float* pp = proto + (((size_t)b * HP + y) * WP + xl) * KK + q * 8;
    short8 bfr;
#pragma unroll
    for (int j = 0; j < 8; j++) bfr[j] = (short)f32_to_bf16(pp[j]);

    float s1 = 0.0f, s2 = 0.0f;
#pragma unroll 2
    for (int c = 0; c < NCH; c++) {
        short8 a = af[c * 64 + L];
        floatx4 d = {0.0f, 0.0f, 0.0f, 0.0f};
        d = __builtin_amdgcn_mfma_f32_16x16x32_bf16(a, bfr, d, 0, 0, 0);
#pragma unroll
        for (int r = 0; r < 4; r++) {
            const int det = c * 16 + q * 4 + r;
            const float gxv = gx[det * WPAD + x0 + c15];
            const float gyv = gyc[det];
            const float sig = __fdividef(1.0f, 1.0f + __expf(-d[r]));
            const float mc  = sig * gxv * gyv;
            s1 += mc;
            s2 = fmaf(mc, mc, s2);
        }
    }
    // reduce partial sums across the 4 quads (same pixel = same lane&15)
    s1 += __shfl_xor(s1, 16, 64);
    s2 += __shfl_xor(s2, 16, 64);
    s1 += __shfl_xor(s1, 32, 64);
    s2 += __shfl_xor(s2, 32, 64);
    if (q == 0 && x0 + c15 < WP) {
        float f = 1.0f - s2 / (s1 + POSEPS);
        if (isnan(f)) f = 0.0f;
        fconf[(size_t)(y * WP + x0 + c15) * BB + b] = f;
    }
}

// ---------------------------------------------------------------------------
// var: bilinear resize + weighted mean/var, algebraic single-pass form:
//   sum_b r*(o-m)^2 = sum(r*o^2) - (sum(r*o))^2 / t
// ---------------------------------------------------------------------------
__global__ __launch_bounds__(256) void var_kernel(
    const float* __restrict__ original, // [B,C,H0,W0]
    const float* __restrict__ fconf,    // [NP][BB]
    float* __restrict__ out)
{
    const int p = blockIdx.x * 256 + threadIdx.x;
    float v = 0.0f;
    if (p < NPIX) {
        const int i = p / W0;
        const int j = p - i * W0;
        const float sc  = (float)HP / (float)H0;
        const float syf = (i + 0.5f) * sc - 0.5f;
        const float sxf = (j + 0.5f) * sc - 0.5f;
        const float fy0 = floorf(syf);
        const float fx0 = floorf(sxf);
        const float wy = syf - fy0;
        const float wx = sxf - fx0;
        const int y0 = max((int)fy0, 0);
        const int x0 = max((int)fx0, 0);
        const int y1 = min((int)fy0 + 1, HP - 1);
        const int x1 = min((int)fx0 + 1, WP - 1);

        const floatx4* F = (const floatx4*)fconf;  // 2 float4 per pixel
        const int i00 = (y0 * WP + x0) * 2;
        const int i01 = (y0 * WP + x1) * 2;
        const int i10 = (y1 * WP + x0) * 2;
        const int i11 = (y1 * WP + x1) * 2;
        const float w00 = (1.0f - wy) * (1.0f - wx);
        const float w01 = (1.0f - wy) * wx;
        const float w10 = wy * (1.0f - wx);
        const float w11 = wy * wx;

        float r[BB];
        float t = 0.0f;
#pragma unroll
        for (int h = 0; h < 2; h++) {
            floatx4 a00 = F[i00 + h], a01 = F[i01 + h];
            floatx4 a10 = F[i10 + h], a11 = F[i11 + h];
#pragma unroll
            for (int e = 0; e < 4; e++) {
                float rb = w00 * a00[e] + w01 * a01[e] + w10 * a10[e] + w11 * a11[e];
                r[4 * h + e] = rb;
                t += rb;
            }
        }
        const float inv_t  = __fdividef(1.0f, t);           // mean divisor (no eps)
        const float inv_te = __fdividef(1.0f, t + POSEPS);  // var divisor (+eps)
        float acc = 0.0f;
#pragma unroll
        for (int c = 0; c < CC; c++) {
            float sro = 0.0f, sroo = 0.0f;
#pragma unroll
            for (int bb = 0; bb < BB; bb++) {
                const float o  = original[(size_t)(bb * CC + c) * NPIX + p];
                const float ro = r[bb] * o;
                sro += ro;
                sroo = fmaf(ro, o, sroo);
            }
            acc += sroo - sro * sro * inv_t;
        }
        v = acc * inv_te;
    }
    // block reduction
    for (int off = 32; off > 0; off >>= 1) v += __shfl_down(v, off, 64);
    __shared__ float red[4];
    const int lane = threadIdx.x & 63;
    const int wid  = threadIdx.x >> 6;
    if (lane == 0) red[wid] = v;
    __syncthreads();
    if (threadIdx.x == 0) {
        const float s = red[0] + red[1] + red[2] + red[3];
        atomicAdd(out, s * 0.25f);  // / K * B = *8/32
    }
}

// ---------------------------------------------------------------------------
extern "C" void kernel_launch(void* const* d_in, const int* in_sizes, int n_in,
                              void* d_out, int out_size, void* d_ws, size_t ws_size,
                              hipStream_t stream) {
    const float* original = (const float*)d_in[0]; // [8,3,550,550]
    const float* loc      = (const float*)d_in[1]; // [8,200,4]
    const float* mask     = (const float*)d_in[2]; // [8,200,32]
    const float* conf     = (const float*)d_in[3]; // [8,200]
    const float* proto    = (const float*)d_in[4]; // [8,138,138,32]
    float* out = (float*)d_out;
    char* ws = (char*)d_ws;
    float* fconf = (float*)(ws + OFF_FCONF);

    hipMemsetAsync(out, 0, sizeof(float), stream);

    const int prep_total = BB * NDP * WPAD + BB * HP * NDP + BB * NCH * 64; // 475,904
    prep_kernel<<<(prep_total + 255) / 256, 256, 0, stream>>>(loc, conf, mask, ws);

    // 8 b * 138 y * 9 xtiles = 9936 waves, 4 waves/block
    conf_kernel<<<(BB * HP * NXT) / 4, 256, 0, stream>>>(proto, ws, fconf);

    var_kernel<<<(NPIX + 255) / 256, 256, 0, stream>>>(original, fconf, out);
}

// Round 3
// 123.465 us; speedup vs baseline: 1.4627x; 1.0342x over previous
//
#include <hip/hip_runtime.h>
#include <math.h>

// Problem constants
#define BB   8
#define NDET 200
#define NDP  208      // dets padded to 13*16
#define NCH  13       // det chunks of 16
#define KK   32
#define HP   138
#define WP   138
#define NXT  9        // x tiles of 16 (covers 144 >= 138)
#define NYP  69       // row pairs
#define NP   (HP*WP)
#define H0   550
#define W0   550
#define NPIX (H0*W0)
#define CC   3
#define POSEPS 1e-6f

typedef __attribute__((ext_vector_type(8))) short  short8;
typedef __attribute__((ext_vector_type(4))) float  floatx4;

// Workspace layout (bytes):
//  afrag: BB*NCH*64*16                = 106,496 @ 0          bf16 A-frags of mask
//  gxT:   BB*WP*NDP*4  (det-inner!)   = 918,528 @ 106,496    exp(-dx^2*ia)
//  gyc:   BB*HP*NDP*4  (det-inner)    = 918,528 @ 1,025,024  conf*exp(-dy^2*ib)
//  fconf: NP*BB*4      (batch-inner)  = 609,408 @ 1,943,552
#define OFF_AFRAG 0
#define OFF_GX    106496
#define OFF_GYC   1025024
#define OFF_FCONF 1943552

__device__ inline unsigned short f32_to_bf16(float f) {
    union { float f; unsigned u; } v; v.f = f;
    unsigned r = v.u + 0x7FFFu + ((v.u >> 16) & 1u);   // RNE
    return (unsigned short)(r >> 16);
}

// ---------------------------------------------------------------------------
// prep: gaussian tables (det-inner layouts) + bf16 mask A-fragments + out=0
// ---------------------------------------------------------------------------
__global__ __launch_bounds__(256) void prep_kernel(
    const float* __restrict__ loc,   // [B,NDET,4]
    const float* __restrict__ conf,  // [B,NDET]
    const float* __restrict__ mask,  // [B,NDET,KK]
    char* __restrict__ ws,
    float* __restrict__ out)
{
    const int idx = blockIdx.x * 256 + threadIdx.x;
    if (idx == 0) out[0] = 0.0f;     // replaces a memset dispatch
    const int W1 = BB * WP * NDP;    // 229,632 gxT
    const int W2 = BB * HP * NDP;    // 229,632 gyc
    if (idx < W1) {
        int b = idx / (WP * NDP); int r = idx - b * (WP * NDP);
        int x = r / NDP;          int n = r - x * NDP;
        float v = 0.0f;
        if (n < NDET) {
            const float* l = loc + (b * NDET + n) * 4;
            float cx = l[0];
            float w  = fmaxf(l[2], 1e-3f);
            float ia = 1.0f / (2.0f * w * w);
            float dx = (x + 0.5f) * (1.0f / WP) - cx;
            v = __expf(-dx * dx * ia);
        }
        ((float*)(ws + OFF_GX))[idx] = v;
    } else if (idx < W1 + W2) {
        int k = idx - W1;
        int b = k / (HP * NDP); int r = k - b * (HP * NDP);
        int y = r / NDP;        int n = r - y * NDP;
        float v = 0.0f;
        if (n < NDET) {
            const float* l = loc + (b * NDET + n) * 4;
            float cy = l[1];
            float h  = fmaxf(l[3], 1e-3f);
            float ib = 1.0f / (2.0f * h * h);
            float dy = (y + 0.5f) * (1.0f / HP) - cy;
            v = conf[b * NDET + n] * __expf(-dy * dy * ib);
        }
        ((float*)(ws + OFF_GYC))[k] = v;
    } else if (idx < W1 + W2 + BB * NCH * 64) {
        int k = idx - W1 - W2;         // (b*NCH + c)*64 + L
        int L = k & 63; int bc = k >> 6;
        int c = bc % NCH; int b = bc / NCH;
        int det = c * 16 + (L & 15);
        int k0  = (L >> 4) * 8;
        unsigned o[4] = {0u, 0u, 0u, 0u};
        if (det < NDET) {
            const float* m = mask + (b * NDET + det) * KK + k0;
#pragma unroll
            for (int j = 0; j < 4; j++) {
                unsigned lo = f32_to_bf16(m[2 * j]);
                unsigned hi = f32_to_bf16(m[2 * j + 1]);
                o[j] = lo | (hi << 16);
            }
        }
        unsigned* dst = (unsigned*)(ws + OFF_AFRAG) + k * 4;
        dst[0] = o[0]; dst[1] = o[1]; dst[2] = o[2]; dst[3] = o[3];
    }
}

// ---------------------------------------------------------------------------
// conf (hot): one wave = a ROW-PAIR (y0r,y1r) x 16 pixels x 208 dets.
// Two mfma_f32_16x16x32_bf16 per det-chunk sharing the A-fragment.
// D mapping: pixel = lane&15, det-in-chunk = (lane>>4)*4 + reg.
// Gaussian tables det-inner -> one dwordx4 per lane per chunk per table.
// ---------------------------------------------------------------------------
__global__ __launch_bounds__(256) void conf_kernel(
    const float* __restrict__ proto,  // [B,HP,WP,KK]
    const char* __restrict__ ws,
    float* __restrict__ fconf)        // [NP][BB]
{
    const int w   = blockIdx.x * 4 + (threadIdx.x >> 6);
    const int L   = threadIdx.x & 63;
    const int b   = w / (NYP * NXT);
    int rem       = w - b * (NYP * NXT);
    const int yp  = rem / NXT;
    const int xt  = rem - yp * NXT;
    const int y0r = yp * 2, y1r = y0r + 1;
    const int x0  = xt * 16;
    const int q   = L >> 4;
    const int c15 = L & 15;
    const int xl  = min(x0 + c15, WP - 1);   // clamp (discarded on store)

    const short8*  af  = (const short8*)(ws + OFF_AFRAG) + (size_t)b * NCH * 64;
    const floatx4* gx4 = (const floatx4*)(ws + OFF_GX)  + ((size_t)b * WP + xl) * (NDP / 4);
    const floatx4* gy0 = (const floatx4*)(ws + OFF_GYC) + ((size_t)b * HP + y0r) * (NDP / 4);
    const floatx4* gy1 = (const floatx4*)(ws + OFF_GYC) + ((size_t)b * HP + y1r) * (NDP / 4);

    // B fragments: proto[b][y][xl][q*8 .. q*8+7] for both rows
    const float* pp0 = proto + (((size_t)b * HP + y0r) * WP + xl) * KK + q * 8;
    const float* pp1 = pp0 + (size_t)WP * KK;
    short8 bf0, bf1;
#pragma unroll
    for (int j = 0; j < 8; j++) {
        bf0[j] = (short)f32_to_bf16(pp0[j]);
        bf1[j] = (short)f32_to_bf16(pp1[j]);
    }

    float s10 = 0.f, s20 = 0.f, s11 = 0.f, s21 = 0.f;
#pragma unroll 2
    for (int c = 0; c < NCH; c++) {
        short8 a = af[c * 64 + L];
        floatx4 d0 = {0.f, 0.f, 0.f, 0.f};
        floatx4 d1 = {0.f, 0.f, 0.f, 0.f};
        d0 = __builtin_amdgcn_mfma_f32_16x16x32_bf16(a, bf0, d0, 0, 0, 0);
        d1 = __builtin_amdgcn_mfma_f32_16x16x32_bf16(a, bf1, d1, 0, 0, 0);
        const floatx4 gxv  = gx4[c * 4 + q];
        const floatx4 gy0v = gy0[c * 4 + q];
        const floatx4 gy1v = gy1[c * 4 + q];
#pragma unroll
        for (int r = 0; r < 4; r++) {
            const float e0   = __expf(-d0[r]);
            const float sig0 = e0 * __frcp_rn(1.0f + e0) ;
            const float mc0  = sig0 * (gxv[r] * gy0v[r]);
            s10 += mc0;
            s20 = fmaf(mc0, mc0, s20);
            const float e1   = __expf(-d1[r]);
            const float sig1 = e1 * __frcp_rn(1.0f + e1);
            const float mc1  = sig1 * (gxv[r] * gy1v[r]);
            s11 += mc1;
            s21 = fmaf(mc1, mc1, s21);
        }
    }
    // reduce across the 4 quads (same pixel = same lane&15)
    s10 += __shfl_xor(s10, 16, 64); s10 += __shfl_xor(s10, 32, 64);
    s20 += __shfl_xor(s20, 16, 64); s20 += __shfl_xor(s20, 32, 64);
    s11 += __shfl_xor(s11, 16, 64); s11 += __shfl_xor(s11, 32, 64);
    s21 += __shfl_xor(s21, 16, 64); s21 += __shfl_xor(s21, 32, 64);
    if (q == 0 && x0 + c15 < WP) {
        float f0 = 1.0f - s20 / (s10 + POSEPS);
        float f1 = 1.0f - s21 / (s11 + POSEPS);
        if (isnan(f0)) f0 = 0.0f;
        if (isnan(f1)) f1 = 0.0f;
        fconf[((size_t)y0r * WP + x0 + c15) * BB + b] = f0;
        fconf[((size_t)y1r * WP + x0 + c15) * BB + b] = f1;
    }
}

// ---------------------------------------------------------------------------
// var: one block per output row. y-interp params are block-uniform; the two
// fconf source rows are staged in LDS (8.8 KB). Single-pass variance:
//   sum_b r*(o-m)^2 = sum(r*o^2) - (sum(r*o))^2 / t
// ---------------------------------------------------------------------------
__global__ __launch_bounds__(256) void var_kernel(
    const float* __restrict__ original, // [B,C,H0,W0]
    const float* __restrict__ fconf,    // [NP][BB]
    float* __restrict__ out)
{
    const int i = blockIdx.x;           // output row
    const float sc  = (float)HP / (float)H0;
    const float syf = (i + 0.5f) * sc - 0.5f;
    const float fy0 = floorf(syf);
    const float wy  = syf - fy0;
    const int y0 = max((int)fy0, 0);
    const int y1 = min((int)fy0 + 1, HP - 1);

    __shared__ float lds[2 * WP * BB];  // 2 rows x 138 px x 8 batches
    {
        const floatx4* s0 = (const floatx4*)(fconf + (size_t)y0 * WP * BB);
        const floatx4* s1 = (const floatx4*)(fconf + (size_t)y1 * WP * BB);
        floatx4* l4 = (floatx4*)lds;
        for (int t = threadIdx.x; t < WP * 2; t += 256) {
            l4[t] = s0[t];
            l4[WP * 2 + t] = s1[t];
        }
    }
    __syncthreads();
    const floatx4* l4 = (const floatx4*)lds;

    float v = 0.0f;
    for (int j = threadIdx.x; j < W0; j += 256) {
        const float sxf = (j + 0.5f) * sc - 0.5f;
        const float fx0 = floorf(sxf);
        const float wx  = sxf - fx0;
        const int x0 = max((int)fx0, 0);
        const int x1 = min((int)fx0 + 1, WP - 1);

        const floatx4 a00 = l4[x0 * 2],          b00 = l4[x0 * 2 + 1];
        const floatx4 a01 = l4[x1 * 2],          b01 = l4[x1 * 2 + 1];
        const floatx4 a10 = l4[WP * 2 + x0 * 2], b10 = l4[WP * 2 + x0 * 2 + 1];
        const floatx4 a11 = l4[WP * 2 + x1 * 2], b11 = l4[WP * 2 + x1 * 2 + 1];
        const float w00 = (1.0f - wy) * (1.0f - wx);
        const float w01 = (1.0f - wy) * wx;
        const float w10 = wy * (1.0f - wx);
        const float w11 = wy * wx;

        float r[BB];
        float t = 0.0f;
#pragma unroll
        for (int e = 0; e < 4; e++) {
            float rb = w00 * a00[e] + w01 * a01[e] + w10 * a10[e] + w11 * a11[e];
            r[e] = rb; t += rb;
        }
#pragma unroll
        for (int e = 0; e < 4; e++) {
            float rb = w00 * b00[e] + w01 * b01[e] + w10 * b10[e] + w11 * b11[e];
            r[4 + e] = rb; t += rb;
        }
        const float inv_t  = __fdividef(1.0f, t);           // mean divisor (no eps)
        const float inv_te = __fdividef(1.0f, t + POSEPS);  // var divisor (+eps)
        float acc = 0.0f;
#pragma unroll
        for (int c = 0; c < CC; c++) {
            float sro = 0.0f, sroo = 0.0f;
#pragma unroll
            for (int bb = 0; bb < BB; bb++) {
                const float o  = original[(size_t)(bb * CC + c) * NPIX + (size_t)i * W0 + j];
                const float ro = r[bb] * o;
                sro += ro;
                sroo = fmaf(ro, o, sroo);
            }
            acc += sroo - sro * sro * inv_t;
        }
        v += acc * inv_te;
    }
    // block reduction
    for (int off = 32; off > 0; off >>= 1) v += __shfl_down(v, off, 64);
    __shared__ float red[4];
    const int lane = threadIdx.x & 63;
    const int wid  = threadIdx.x >> 6;
    if (lane == 0) red[wid] = v;
    __syncthreads();
    if (threadIdx.x == 0) {
        const float s = red[0] + red[1] + red[2] + red[3];
        atomicAdd(out, s * 0.25f);  // / K * B = * 8/32
    }
}

// ---------------------------------------------------------------------------
extern "C" void kernel_launch(void* const* d_in, const int* in_sizes, int n_in,
                              void* d_out, int out_size, void* d_ws, size_t ws_size,
                              hipStream_t stream) {
    const float* original = (const float*)d_in[0]; // [8,3,550,550]
    const float* loc      = (const float*)d_in[1]; // [8,200,4]
    const float* mask     = (const float*)d_in[2]; // [8,200,32]
    const float* conf     = (const float*)d_in[3]; // [8,200]
    const float* proto    = (const float*)d_in[4]; // [8,138,138,32]
    float* out = (float*)d_out;
    char* ws = (char*)d_ws;
    float* fconf = (float*)(ws + OFF_FCONF);

    const int prep_total = BB * WP * NDP + BB * HP * NDP + BB * NCH * 64; // 465,920
    prep_kernel<<<(prep_total + 255) / 256, 256, 0, stream>>>(loc, conf, mask, ws, out);

    // 8 b * 69 row-pairs * 9 xtiles = 4968 waves, 4 waves/block
    conf_kernel<<<(BB * NYP * NXT) / 4, 256, 0, stream>>>(proto, ws, fconf);

    var_kernel<<<H0, 256, 0, stream>>>(original, fconf, out);
}

// Round 4
// 114.077 us; speedup vs baseline: 1.5831x; 1.0823x over previous
//
#include <hip/hip_runtime.h>
#include <math.h>

// Problem constants
#define BB   8
#define NDET 200
#define NDP  208      // dets padded to 13*16
#define NCH  13       // det chunks of 16
#define KK   32
#define HP   138
#define WP   138
#define NXT  9        // x tiles of 16 (covers 144 >= 138)
#define NYP  69       // row pairs
#define NP   (HP*WP)
#define H0   550
#define W0   550
#define NPIX (H0*W0)
#define CC   3
#define POSEPS 1e-6f

typedef __attribute__((ext_vector_type(8))) short  short8;
typedef __attribute__((ext_vector_type(4))) float  floatx4;

// Workspace layout (bytes):
//  afrag: BB*NCH*64*16                = 106,496 @ 0          bf16 A-frags of mask
//  gxT:   BB*WP*NDP*4  (det-inner)    = 918,528 @ 106,496    exp(-dx^2*ia)
//  gyc:   BB*HP*NDP*4  (det-inner)    = 918,528 @ 1,025,024  conf*exp(-dy^2*ib)
//  fconf: NP*BB*4      (batch-inner)  = 609,408 @ 1,943,552
#define OFF_AFRAG 0
#define OFF_GX    106496
#define OFF_GYC   1025024
#define OFF_FCONF 1943552

extern "C" __device__ float __builtin_amdgcn_rcpf(float);  // v_rcp_f32

__device__ inline unsigned short f32_to_bf16(float f) {
    union { float f; unsigned u; } v; v.f = f;
    unsigned r = v.u + 0x7FFFu + ((v.u >> 16) & 1u);   // RNE
    return (unsigned short)(r >> 16);
}

// ---------------------------------------------------------------------------
// prep: gaussian tables (det-inner layouts) + bf16 mask A-fragments + out=0
// ---------------------------------------------------------------------------
__global__ __launch_bounds__(256) void prep_kernel(
    const float* __restrict__ loc,   // [B,NDET,4]
    const float* __restrict__ conf,  // [B,NDET]
    const float* __restrict__ mask,  // [B,NDET,KK]
    char* __restrict__ ws,
    float* __restrict__ out)
{
    const int idx = blockIdx.x * 256 + threadIdx.x;
    if (idx == 0) out[0] = 0.0f;     // replaces a memset dispatch
    const int W1 = BB * WP * NDP;    // 229,632 gxT
    const int W2 = BB * HP * NDP;    // 229,632 gyc
    if (idx < W1) {
        int b = idx / (WP * NDP); int r = idx - b * (WP * NDP);
        int x = r / NDP;          int n = r - x * NDP;
        float v = 0.0f;
        if (n < NDET) {
            const float* l = loc + (b * NDET + n) * 4;
            float cx = l[0];
            float w  = fmaxf(l[2], 1e-3f);
            float ia = 1.0f / (2.0f * w * w);
            float dx = (x + 0.5f) * (1.0f / WP) - cx;
            v = __expf(-dx * dx * ia);
        }
        ((float*)(ws + OFF_GX))[idx] = v;
    } else if (idx < W1 + W2) {
        int k = idx - W1;
        int b = k / (HP * NDP); int r = k - b * (HP * NDP);
        int y = r / NDP;        int n = r - y * NDP;
        float v = 0.0f;
        if (n < NDET) {
            const float* l = loc + (b * NDET + n) * 4;
            float cy = l[1];
            float h  = fmaxf(l[3], 1e-3f);
            float ib = 1.0f / (2.0f * h * h);
            float dy = (y + 0.5f) * (1.0f / HP) - cy;
            v = conf[b * NDET + n] * __expf(-dy * dy * ib);
        }
        ((float*)(ws + OFF_GYC))[k] = v;
    } else if (idx < W1 + W2 + BB * NCH * 64) {
        int k = idx - W1 - W2;         // (b*NCH + c)*64 + L
        int L = k & 63; int bc = k >> 6;
        int c = bc % NCH; int b = bc / NCH;
        int det = c * 16 + (L & 15);
        int k0  = (L >> 4) * 8;
        unsigned o[4] = {0u, 0u, 0u, 0u};
        if (det < NDET) {
            const float* m = mask + (b * NDET + det) * KK + k0;
#pragma unroll
            for (int j = 0; j < 4; j++) {
                unsigned lo = f32_to_bf16(m[2 * j]);
                unsigned hi = f32_to_bf16(m[2 * j + 1]);
                o[j] = lo | (hi << 16);
            }
        }
        unsigned* dst = (unsigned*)(ws + OFF_AFRAG) + k * 4;
        dst[0] = o[0]; dst[1] = o[1]; dst[2] = o[2]; dst[3] = o[3];
    }
}

// ---------------------------------------------------------------------------
// conf (hot): one wave = a ROW-PAIR (y0r,y1r) x 16 pixels x 208 dets.
// Two mfma_f32_16x16x32_bf16 per det-chunk sharing the A-fragment.
// D mapping: pixel = lane&15, det-in-chunk = (lane>>4)*4 + reg.
// sigmoid(d) = v_rcp(1 + exp(-d)): 2 trans + 1 VALU per element.
// ---------------------------------------------------------------------------
__global__ __launch_bounds__(256) void conf_kernel(
    const float* __restrict__ proto,  // [B,HP,WP,KK]
    const char* __restrict__ ws,
    float* __restrict__ fconf)        // [NP][BB]
{
    const int w   = blockIdx.x * 4 + (threadIdx.x >> 6);
    const int L   = threadIdx.x & 63;
    const int b   = w / (NYP * NXT);
    int rem       = w - b * (NYP * NXT);
    const int yp  = rem / NXT;
    const int xt  = rem - yp * NXT;
    const int y0r = yp * 2, y1r = y0r + 1;
    const int x0  = xt * 16;
    const int q   = L >> 4;
    const int c15 = L & 15;
    const int xl  = min(x0 + c15, WP - 1);   // clamp (discarded on store)

    const short8*  af  = (const short8*)(ws + OFF_AFRAG) + (size_t)b * NCH * 64;
    const floatx4* gx4 = (const floatx4*)(ws + OFF_GX)  + ((size_t)b * WP + xl) * (NDP / 4);
    const floatx4* gy0 = (const floatx4*)(ws + OFF_GYC) + ((size_t)b * HP + y0r) * (NDP / 4);
    const floatx4* gy1 = (const floatx4*)(ws + OFF_GYC) + ((size_t)b * HP + y1r) * (NDP / 4);

    // B fragments: proto[b][y][xl][q*8 .. q*8+7] for both rows
    const float* pp0 = proto + (((size_t)b * HP + y0r) * WP + xl) * KK + q * 8;
    const float* pp1 = pp0 + (size_t)WP * KK;
    short8 bf0, bf1;
#pragma unroll
    for (int j = 0; j < 8; j++) {
        bf0[j] = (short)f32_to_bf16(pp0[j]);
        bf1[j] = (short)f32_to_bf16(pp1[j]);
    }

    float s10 = 0.f, s20 = 0.f, s11 = 0.f, s21 = 0.f;
#pragma unroll 2
    for (int c = 0; c < NCH; c++) {
        short8 a = af[c * 64 + L];
        floatx4 d0 = {0.f, 0.f, 0.f, 0.f};
        floatx4 d1 = {0.f, 0.f, 0.f, 0.f};
        d0 = __builtin_amdgcn_mfma_f32_16x16x32_bf16(a, bf0, d0, 0, 0, 0);
        d1 = __builtin_amdgcn_mfma_f32_16x16x32_bf16(a, bf1, d1, 0, 0, 0);
        const floatx4 gxv  = gx4[c * 4 + q];
        const floatx4 gy0v = gy0[c * 4 + q];
        const floatx4 gy1v = gy1[c * 4 + q];
#pragma unroll
        for (int r = 0; r < 4; r++) {
            // sigmoid(d) = 1/(1+exp(-d))  (single v_rcp_f32, 1ulp-ish: fine
            // under the 2%-relative scalar threshold)
            const float sig0 = __builtin_amdgcn_rcpf(1.0f + __expf(-d0[r]));
            const float mc0  = sig0 * (gxv[r] * gy0v[r]);
            s10 += mc0;
            s20 = fmaf(mc0, mc0, s20);
            const float sig1 = __builtin_amdgcn_rcpf(1.0f + __expf(-d1[r]));
            const float mc1  = sig1 * (gxv[r] * gy1v[r]);
            s11 += mc1;
            s21 = fmaf(mc1, mc1, s21);
        }
    }
    // reduce across the 4 quads (same pixel = same lane&15)
    s10 += __shfl_xor(s10, 16, 64); s10 += __shfl_xor(s10, 32, 64);
    s20 += __shfl_xor(s20, 16, 64); s20 += __shfl_xor(s20, 32, 64);
    s11 += __shfl_xor(s11, 16, 64); s11 += __shfl_xor(s11, 32, 64);
    s21 += __shfl_xor(s21, 16, 64); s21 += __shfl_xor(s21, 32, 64);
    if (q == 0 && x0 + c15 < WP) {
        float f0 = 1.0f - s20 / (s10 + POSEPS);
        float f1 = 1.0f - s21 / (s11 + POSEPS);
        if (isnan(f0)) f0 = 0.0f;
        if (isnan(f1)) f1 = 0.0f;
        fconf[((size_t)y0r * WP + x0 + c15) * BB + b] = f0;
        fconf[((size_t)y1r * WP + x0 + c15) * BB + b] = f1;
    }
}

// ---------------------------------------------------------------------------
// var: one block per output row. y-interp params are block-uniform; the two
// fconf source rows are staged in LDS (8.8 KB). Single-pass variance:
//   sum_b r*(o-m)^2 = sum(r*o^2) - (sum(r*o))^2 / t
// ---------------------------------------------------------------------------
__global__ __launch_bounds__(256) void var_kernel(
    const float* __restrict__ original, // [B,C,H0,W0]
    const float* __restrict__ fconf,    // [NP][BB]
    float* __restrict__ out)
{
    const int i = blockIdx.x;           // output row
    const float sc  = (float)HP / (float)H0;
    const float syf = (i + 0.5f) * sc - 0.5f;
    const float fy0 = floorf(syf);
    const float wy  = syf - fy0;
    const int y0 = max((int)fy0, 0);
    const int y1 = min((int)fy0 + 1, HP - 1);

    __shared__ float lds[2 * WP * BB];  // 2 rows x 138 px x 8 batches
    {
        const floatx4* s0 = (const floatx4*)(fconf + (size_t)y0 * WP * BB);
        const floatx4* s1 = (const floatx4*)(fconf + (size_t)y1 * WP * BB);
        floatx4* l4 = (floatx4*)lds;
        for (int t = threadIdx.x; t < WP * 2; t += 256) {
            l4[t] = s0[t];
            l4[WP * 2 + t] = s1[t];
        }
    }
    __syncthreads();
    const floatx4* l4 = (const floatx4*)lds;

    float v = 0.0f;
    for (int j = threadIdx.x; j < W0; j += 256) {
        const float sxf = (j + 0.5f) * sc - 0.5f;
        const float fx0 = floorf(sxf);
        const float wx  = sxf - fx0;
        const int x0 = max((int)fx0, 0);
        const int x1 = min((int)fx0 + 1, WP - 1);

        const floatx4 a00 = l4[x0 * 2],          b00 = l4[x0 * 2 + 1];
        const floatx4 a01 = l4[x1 * 2],          b01 = l4[x1 * 2 + 1];
        const floatx4 a10 = l4[WP * 2 + x0 * 2], b10 = l4[WP * 2 + x0 * 2 + 1];
        const floatx4 a11 = l4[WP * 2 + x1 * 2], b11 = l4[WP * 2 + x1 * 2 + 1];
        const float w00 = (1.0f - wy) * (1.0f - wx);
        const float w01 = (1.0f - wy) * wx;
        const float w10 = wy * (1.0f - wx);
        const float w11 = wy * wx;

        float r[BB];
        float t = 0.0f;
#pragma unroll
        for (int e = 0; e < 4; e++) {
            float rb = w00 * a00[e] + w01 * a01[e] + w10 * a10[e] + w11 * a11[e];
            r[e] = rb; t += rb;
        }
#pragma unroll
        for (int e = 0; e < 4; e++) {
            float rb = w00 * b00[e] + w01 * b01[e] + w10 * b10[e] + w11 * b11[e];
            r[4 + e] = rb; t += rb;
        }
        const float inv_t  = __fdividef(1.0f, t);           // mean divisor (no eps)
        const float inv_te = __fdividef(1.0f, t + POSEPS);  // var divisor (+eps)
        float acc = 0.0f;
#pragma unroll
        for (int c = 0; c < CC; c++) {
            float sro = 0.0f, sroo = 0.0f;
#pragma unroll
            for (int bb = 0; bb < BB; bb++) {
                const float o  = original[(size_t)(bb * CC + c) * NPIX + (size_t)i * W0 + j];
                const float ro = r[bb] * o;
                sro += ro;
                sroo = fmaf(ro, o, sroo);
            }
            acc += sroo - sro * sro * inv_t;
        }
        v += acc * inv_te;
    }
    // block reduction
    for (int off = 32; off > 0; off >>= 1) v += __shfl_down(v, off, 64);
    __shared__ float red[4];
    const int lane = threadIdx.x & 63;
    const int wid  = threadIdx.x >> 6;
    if (lane == 0) red[wid] = v;
    __syncthreads();
    if (threadIdx.x == 0) {
        const float s = red[0] + red[1] + red[2] + red[3];
        atomicAdd(out, s * 0.25f);  // / K * B = * 8/32
    }
}

// ---------------------------------------------------------------------------
extern "C" void kernel_launch(void* const* d_in, const int* in_sizes, int n_in,
                              void* d_out, int out_size, void* d_ws, size_t ws_size,
                              hipStream_t stream) {
    const float* original = (const float*)d_in[0]; // [8,3,550,550]
    const float* loc      = (const float*)d_in[1]; // [8,200,4]
    const float* mask     = (const float*)d_in[2]; // [8,200,32]
    const float* conf     = (const float*)d_in[3]; // [8,200]
    const float* proto    = (const float*)d_in[4]; // [8,138,138,32]
    float* out = (float*)d_out;
    char* ws = (char*)d_ws;
    float* fconf = (float*)(ws + OFF_FCONF);

    const int prep_total = BB * WP * NDP + BB * HP * NDP + BB * NCH * 64; // 465,920
    prep_kernel<<<(prep_total + 255) / 256, 256, 0, stream>>>(loc, conf, mask, ws, out);

    // 8 b * 69 row-pairs * 9 xtiles = 4968 waves, 4 waves/block
    conf_kernel<<<(BB * NYP * NXT) / 4, 256, 0, stream>>>(proto, ws, fconf);

    var_kernel<<<H0, 256, 0, stream>>>(original, fconf, out);
}